// Round 9
// baseline (3379.659 us; speedup 1.0000x reference)
//
#include <hip/hip_runtime.h>

// SimpleLSTM B=256, T=512, I=3, H=512. out = fc(h_T).
// R9 = R8 (known-pass, 2.50ms) + three isolated fixes:
//  1. W LDS layout -> fragment-linear (lane l reads base + l*16B, conflict-free)
//  2. gates2 padding 17 -> 20 (uniform 2-way bank aliasing = free)
//  3. barrier exit: all waves poll counter directly (no post-poll syncthreads)
// Decomposition unchanged: 256 wgs x 512 thr, wg (bb=wg&7, hb=wg>>3),
// waves (m: batch half, ks: K quarter), split-bf16 MFMA, batched GLOAD sc0sc1,
// atomic h-stores, per-group LLC counter barrier.

#define Hh   512
#define Bsz  256
#define Tt   512

#define MB   32
#define HS   16
#define NROW 64
#define NTHR 512
#define NWG  256

typedef float f32x4 __attribute__((ext_vector_type(4)));
typedef short s16x8 __attribute__((ext_vector_type(8)));
typedef unsigned long long u64;

#define PLANE_SZ (2 * Bsz * Hh * 2)          // 512 KB
#define HHI_OFF  0
#define HLO_OFF  (HHI_OFF + PLANE_SZ)
#define BAR_OFF  (HLO_OFF + PLANE_SZ)
#define CTRL_UINTS 256

__device__ __forceinline__ float sigm(float v)  { return 1.0f / (1.0f + __expf(-v)); }
__device__ __forceinline__ float tanhx(float v) { return 2.0f / (1.0f + __expf(-2.0f * v)) - 1.0f; }

__device__ __forceinline__ ushort f2bf(float f) {   // RNE
  unsigned u = __float_as_uint(f);
  return (ushort)((u + 0x7FFFu + ((u >> 16) & 1u)) >> 16);
}
__device__ __forceinline__ float bf2f(ushort u) {
  return __uint_as_float((unsigned)u << 16);
}

#define GLOAD(dst, base, imm)                                            \
  asm volatile("global_load_dwordx4 %0, %1, off offset:%c2 sc0 sc1"      \
               : "=v"(dst) : "v"(base), "i"(imm))

// Arrival: drain stores, wg-converge, one increment. Exit: every wave's
// lane 0 polls (relaxed agent load); SIMT reconvergence syncs the wave.
__device__ __forceinline__ void group_barrier(unsigned* bar, int tid, unsigned target) {
  asm volatile("s_waitcnt vmcnt(0)" ::: "memory");
  __syncthreads();
  if (tid == 0)
    __hip_atomic_fetch_add(bar, 1u, __ATOMIC_RELAXED, __HIP_MEMORY_SCOPE_AGENT);
  if ((tid & 63) == 0) {
    while (__hip_atomic_load(bar, __ATOMIC_RELAXED, __HIP_MEMORY_SCOPE_AGENT) < target)
      __builtin_amdgcn_s_sleep(1);
  }
}

__global__ void init_ws(unsigned* ctrl) {
  ctrl[threadIdx.x] = 0u;
}

__global__ __launch_bounds__(NTHR, 2)
void lstm_kernel(const float* __restrict__ x,   const float* __restrict__ Wih,
                 const float* __restrict__ Whh, const float* __restrict__ bih,
                 const float* __restrict__ bhh, const float* __restrict__ fcw,
                 const float* __restrict__ fcb, float* __restrict__ out,
                 char* __restrict__ ws)
{
  const int tid = threadIdx.x;
  const int wg  = blockIdx.x;
  const int bb  = wg & 7;
  const int hb  = wg >> 3;
  const int j0  = hb * HS;
  const int b0  = bb * MB;

  ushort*   hhi = (ushort*)(ws + HHI_OFF);
  ushort*   hlo = (ushort*)(ws + HLO_OFF);
  unsigned* bar = (unsigned*)(ws + BAR_OFF) + bb * 16;

  // Fragment-linear W: whiF[((q*16 + kblk)*64 + lane)*8 + e] =
  //   W[q*16 + (lane&15)][kblk*32 + (lane>>4)*8 + e],  kblk = 0..15
  __shared__ ushort whiF[4 * 16 * 64 * 8];   // 64 KB
  __shared__ ushort wloF[4 * 16 * 64 * 8];   // 64 KB
  __shared__ float  gates2[2][4][MB][20];    // two-stage K-partials, pad 20
  __shared__ float  wih_s[NROW][3];
  __shared__ float  bsum[NROW];
  __shared__ float  xs[MB][3];
  __shared__ ushort hstg[MB][16];
  __shared__ ushort lstg[MB][16];

  if (tid < NROW) {
    int qq = tid >> 4, jj = tid & 15;
    int grow = qq * Hh + j0 + jj;
    wih_s[tid][0] = Wih[grow * 3 + 0];
    wih_s[tid][1] = Wih[grow * 3 + 1];
    wih_s[tid][2] = Wih[grow * 3 + 2];
    bsum[tid] = bih[grow] + bhh[grow];
  }

  for (int idx = tid; idx < NROW * 64; idx += NTHR) {
    int row = idx >> 6, seg = idx & 63;
    int qq = row >> 4, jj = row & 15;
    const float* src = Whh + (size_t)(qq * Hh + j0 + jj) * Hh + seg * 8;
    float4 w0 = *(const float4*)(src);
    float4 w1 = *(const float4*)(src + 4);
    float wv[8] = {w0.x, w0.y, w0.z, w0.w, w1.x, w1.y, w1.z, w1.w};
    unsigned uhi[4], ulo[4];
    #pragma unroll
    for (int p = 0; p < 4; ++p) {
      ushort h0 = f2bf(wv[2*p]),   h1 = f2bf(wv[2*p+1]);
      ushort l0 = f2bf(wv[2*p]   - bf2f(h0));
      ushort l1 = f2bf(wv[2*p+1] - bf2f(h1));
      uhi[p] = (unsigned)h0 | ((unsigned)h1 << 16);
      ulo[p] = (unsigned)l0 | ((unsigned)l1 << 16);
    }
    int kblk = seg >> 2, lkk = seg & 3;
    int dst = ((qq * 16 + kblk) * 64 + lkk * 16 + jj) * 8;
    *(uint4*)&whiF[dst] = make_uint4(uhi[0], uhi[1], uhi[2], uhi[3]);
    *(uint4*)&wloF[dst] = make_uint4(ulo[0], ulo[1], ulo[2], ulo[3]);
  }

  {
    int b = tid >> 4, jj = tid & 15;
    size_t o = (size_t)(b0 + b) * Hh + j0 + jj;
    __hip_atomic_store(&hhi[o], (ushort)0, __ATOMIC_RELAXED, __HIP_MEMORY_SCOPE_AGENT);
    __hip_atomic_store(&hlo[o], (ushort)0, __ATOMIC_RELAXED, __HIP_MEMORY_SCOPE_AGENT);
  }
  group_barrier(bar, tid, 32u);

  const int l   = tid & 63;
  const int wid = tid >> 6;
  const int m   = wid >> 2;            // batch half (0..1)
  const int ks  = wid & 3;             // K quarter (0..3)
  const int lm  = l & 15;
  const int lk  = l >> 4;              // 0..3

  const size_t aoff  = (size_t)(b0 + m * 16 + lm) * Hh + ks * 128 + lk * 8;
  const int    wq0   = ks * 2048 + l * 8;   // + q*8192 + u*512 (ushort idx)

  const int cb = tid >> 4;
  const int cj = tid & 15;
  float c_state = 0.0f;

  int cur = 0;
  for (int t = 0; t < Tt; ++t) {
    if (tid < MB * 3) {
      int b = tid / 3, ii = tid - b * 3;
      xs[b][ii] = x[(size_t)(b0 + b) * (Tt * 3) + t * 3 + ii];
    }

    // ---- 8 pipelined A loads (distinct K-quarter, hi+lo) ----
    const char* pH = (const char*)(hhi + (size_t)cur * Bsz * Hh + aoff);
    const char* pL = (const char*)(hlo + (size_t)cur * Bsz * Hh + aoff);
    f32x4 AH[4], AL[4];
    GLOAD(AH[0], pH, 0);  GLOAD(AH[1], pH, 64);  GLOAD(AH[2], pH, 128); GLOAD(AH[3], pH, 192);
    GLOAD(AL[0], pL, 0);  GLOAD(AL[1], pL, 64);  GLOAD(AL[2], pL, 128); GLOAD(AL[3], pL, 192);
    asm volatile("s_waitcnt vmcnt(0)" ::: "memory");
    __builtin_amdgcn_sched_barrier(0);

    // ---- 4 quadrants x 4 k-blocks x 3 split terms = 48 MFMAs ----
    f32x4 acc0 = {0.f,0.f,0.f,0.f}, acc1 = {0.f,0.f,0.f,0.f};
    f32x4 acc2 = {0.f,0.f,0.f,0.f}, acc3 = {0.f,0.f,0.f,0.f};
    #pragma unroll
    for (int u = 0; u < 4; ++u) {
      s16x8 ah = __builtin_bit_cast(s16x8, AH[u]);
      s16x8 al = __builtin_bit_cast(s16x8, AL[u]);
      const int fo = wq0 + u * 512;
      {
        s16x8 bh = *(const s16x8*)&whiF[0 * 8192 + fo];
        s16x8 bl = *(const s16x8*)&wloF[0 * 8192 + fo];
        acc0 = __builtin_amdgcn_mfma_f32_16x16x32_bf16(ah, bh, acc0, 0, 0, 0);
        acc0 = __builtin_amdgcn_mfma_f32_16x16x32_bf16(ah, bl, acc0, 0, 0, 0);
        acc0 = __builtin_amdgcn_mfma_f32_16x16x32_bf16(al, bh, acc0, 0, 0, 0);
      }
      {
        s16x8 bh = *(const s16x8*)&whiF[1 * 8192 + fo];
        s16x8 bl = *(const s16x8*)&wloF[1 * 8192 + fo];
        acc1 = __builtin_amdgcn_mfma_f32_16x16x32_bf16(ah, bh, acc1, 0, 0, 0);
        acc1 = __builtin_amdgcn_mfma_f32_16x16x32_bf16(ah, bl, acc1, 0, 0, 0);
        acc1 = __builtin_amdgcn_mfma_f32_16x16x32_bf16(al, bh, acc1, 0, 0, 0);
      }
      {
        s16x8 bh = *(const s16x8*)&whiF[2 * 8192 + fo];
        s16x8 bl = *(const s16x8*)&wloF[2 * 8192 + fo];
        acc2 = __builtin_amdgcn_mfma_f32_16x16x32_bf16(ah, bh, acc2, 0, 0, 0);
        acc2 = __builtin_amdgcn_mfma_f32_16x16x32_bf16(ah, bl, acc2, 0, 0, 0);
        acc2 = __builtin_amdgcn_mfma_f32_16x16x32_bf16(al, bh, acc2, 0, 0, 0);
      }
      {
        s16x8 bh = *(const s16x8*)&whiF[3 * 8192 + fo];
        s16x8 bl = *(const s16x8*)&wloF[3 * 8192 + fo];
        acc3 = __builtin_amdgcn_mfma_f32_16x16x32_bf16(ah, bh, acc3, 0, 0, 0);
        acc3 = __builtin_amdgcn_mfma_f32_16x16x32_bf16(ah, bl, acc3, 0, 0, 0);
        acc3 = __builtin_amdgcn_mfma_f32_16x16x32_bf16(al, bh, acc3, 0, 0, 0);
      }
    }

    // ---- two-stage K-partial reduction in LDS ----
    const int rrow = m * 16 + lk * 4;
    if (ks < 2) {
      #pragma unroll
      for (int r = 0; r < 4; ++r) {
        gates2[ks][0][rrow + r][lm] = acc0[r];
        gates2[ks][1][rrow + r][lm] = acc1[r];
        gates2[ks][2][rrow + r][lm] = acc2[r];
        gates2[ks][3][rrow + r][lm] = acc3[r];
      }
    }
    __syncthreads();
    if (ks >= 2) {
      #pragma unroll
      for (int r = 0; r < 4; ++r) {
        gates2[ks - 2][0][rrow + r][lm] += acc0[r];
        gates2[ks - 2][1][rrow + r][lm] += acc1[r];
        gates2[ks - 2][2][rrow + r][lm] += acc2[r];
        gates2[ks - 2][3][rrow + r][lm] += acc3[r];
      }
    }
    __syncthreads();

    // ---- gate combine ----
    {
      float xv0 = xs[cb][0], xv1 = xs[cb][1], xv2 = xs[cb][2];
      float pre[4];
      #pragma unroll
      for (int qq = 0; qq < 4; ++qq) {
        int r = qq * 16 + cj;
        pre[qq] = gates2[0][qq][cb][cj] + gates2[1][qq][cb][cj] + bsum[r]
                + xv0 * wih_s[r][0] + xv1 * wih_s[r][1] + xv2 * wih_s[r][2];
      }
      float ig = sigm(pre[0]), fg = sigm(pre[1]);
      float gg = tanhx(pre[2]), og = sigm(pre[3]);
      c_state = fg * c_state + ig * gg;
      float hv = og * tanhx(c_state);
      ushort uh = f2bf(hv);
      hstg[cb][cj] = uh;
      lstg[cb][cj] = f2bf(hv - bf2f(uh));
    }
    __syncthreads();

    if (tid < 256) {
      int b = tid >> 3, jp = tid & 7;
      unsigned wh = (unsigned)hstg[b][2 * jp] | ((unsigned)hstg[b][2 * jp + 1] << 16);
      unsigned wl = (unsigned)lstg[b][2 * jp] | ((unsigned)lstg[b][2 * jp + 1] << 16);
      size_t wordo = ((size_t)(cur ^ 1) * Bsz * Hh + (size_t)(b0 + b) * Hh + j0) / 2 + jp;
      __hip_atomic_store((unsigned*)hhi + wordo, wh, __ATOMIC_RELAXED, __HIP_MEMORY_SCOPE_AGENT);
      __hip_atomic_store((unsigned*)hlo + wordo, wl, __ATOMIC_RELAXED, __HIP_MEMORY_SCOPE_AGENT);
    }

    group_barrier(bar, tid, 32u * (t + 2));
    cur ^= 1;
  }

  if (hb == 0) {
    const u64* Hf = (const u64*)(hhi + (size_t)cur * Bsz * Hh);
    const u64* Lf = (const u64*)(hlo + (size_t)cur * Bsz * Hh);
    int b = tid >> 4, lj = tid & 15;
    float p = 0.0f;
    for (int jq = lj; jq < Hh / 4; jq += 16) {
      size_t o = (size_t)(b0 + b) * (Hh / 4) + jq;
      u64 uh = __hip_atomic_load(Hf + o, __ATOMIC_RELAXED, __HIP_MEMORY_SCOPE_AGENT);
      u64 ul = __hip_atomic_load(Lf + o, __ATOMIC_RELAXED, __HIP_MEMORY_SCOPE_AGENT);
      #pragma unroll
      for (int e = 0; e < 4; ++e) {
        float hv = bf2f((ushort)(uh >> (16 * e))) + bf2f((ushort)(ul >> (16 * e)));
        p += hv * fcw[4 * jq + e];
      }
    }
    __syncthreads();   // all waves done with gates2 before reuse
    ((float*)gates2)[tid] = p;
    __syncthreads();
    if (lj == 0) {
      float s = 0.0f;
      #pragma unroll
      for (int r = 0; r < 16; ++r) s += ((float*)gates2)[(b << 4) + r];
      out[b0 + b] = s + fcb[0];
    }
  }
}

extern "C" void kernel_launch(void* const* d_in, const int* in_sizes, int n_in,
                              void* d_out, int out_size, void* d_ws, size_t ws_size,
                              hipStream_t stream) {
  const float* x   = (const float*)d_in[0];
  const float* Wih = (const float*)d_in[1];
  const float* Whh = (const float*)d_in[2];
  const float* bih = (const float*)d_in[3];
  const float* bhh = (const float*)d_in[4];
  const float* fcw = (const float*)d_in[5];
  const float* fcb = (const float*)d_in[6];
  float* out = (float*)d_out;
  char*  ws  = (char*)d_ws;

  hipLaunchKernelGGL(init_ws, dim3(1), dim3(CTRL_UINTS), 0, stream,
                     (unsigned*)(ws + BAR_OFF));
  hipLaunchKernelGGL(lstm_kernel, dim3(NWG), dim3(NTHR), 0, stream,
                     x, Wih, Whh, bih, bhh, fcw, fcb, out, ws);
}

// Round 10
// 2458.403 us; speedup vs baseline: 1.3747x; 1.3747x over previous
//
#include <hip/hip_runtime.h>

// SimpleLSTM B=256, T=512, I=3, H=512. out = fc(h_T).
// R10 = R9 with the barrier-exit change REVERTED (that was the R9 regressor:
// 2048 pollers x 256/line contended the LLC counter lines). Barrier is back
// to R8's form: leader polls (s_sleep(2)), __syncthreads broadcasts release.
// Kept from R9 (validated by SQ_LDS_BANK_CONFLICT 2.01e8 -> 1.86e7):
//  - fragment-linear W LDS layout (lane l reads base + l*16B)
//  - gates2 padding 20 (uniform 2-way = free)
// Decomposition: 256 wgs x 512 thr, wg (bb=wg&7, hb=wg>>3), waves (m, ks),
// split-bf16 MFMA, batched GLOAD sc0sc1 + single vmcnt drain, atomic h-stores.

#define Hh   512
#define Bsz  256
#define Tt   512

#define MB   32
#define HS   16
#define NROW 64
#define NTHR 512
#define NWG  256

typedef float f32x4 __attribute__((ext_vector_type(4)));
typedef short s16x8 __attribute__((ext_vector_type(8)));
typedef unsigned long long u64;

#define PLANE_SZ (2 * Bsz * Hh * 2)          // 512 KB
#define HHI_OFF  0
#define HLO_OFF  (HHI_OFF + PLANE_SZ)
#define BAR_OFF  (HLO_OFF + PLANE_SZ)
#define CTRL_UINTS 256

__device__ __forceinline__ float sigm(float v)  { return 1.0f / (1.0f + __expf(-v)); }
__device__ __forceinline__ float tanhx(float v) { return 2.0f / (1.0f + __expf(-2.0f * v)) - 1.0f; }

__device__ __forceinline__ ushort f2bf(float f) {   // RNE
  unsigned u = __float_as_uint(f);
  return (ushort)((u + 0x7FFFu + ((u >> 16) & 1u)) >> 16);
}
__device__ __forceinline__ float bf2f(ushort u) {
  return __uint_as_float((unsigned)u << 16);
}

#define GLOAD(dst, base, imm)                                            \
  asm volatile("global_load_dwordx4 %0, %1, off offset:%c2 sc0 sc1"      \
               : "=v"(dst) : "v"(base), "i"(imm))

// R8-style barrier: drain stores, converge, single increment, leader polls,
// __syncthreads broadcasts release. 256 pollers chip-wide (32 per line).
__device__ __forceinline__ void group_barrier(unsigned* bar, int tid, unsigned target) {
  asm volatile("s_waitcnt vmcnt(0)" ::: "memory");
  __syncthreads();
  if (tid == 0) {
    __hip_atomic_fetch_add(bar, 1u, __ATOMIC_RELAXED, __HIP_MEMORY_SCOPE_AGENT);
    while (__hip_atomic_load(bar, __ATOMIC_RELAXED, __HIP_MEMORY_SCOPE_AGENT) < target)
      __builtin_amdgcn_s_sleep(2);
  }
  __syncthreads();
}

__global__ void init_ws(unsigned* ctrl) {
  ctrl[threadIdx.x] = 0u;
}

__global__ __launch_bounds__(NTHR, 2)
void lstm_kernel(const float* __restrict__ x,   const float* __restrict__ Wih,
                 const float* __restrict__ Whh, const float* __restrict__ bih,
                 const float* __restrict__ bhh, const float* __restrict__ fcw,
                 const float* __restrict__ fcb, float* __restrict__ out,
                 char* __restrict__ ws)
{
  const int tid = threadIdx.x;
  const int wg  = blockIdx.x;
  const int bb  = wg & 7;
  const int hb  = wg >> 3;
  const int j0  = hb * HS;
  const int b0  = bb * MB;

  ushort*   hhi = (ushort*)(ws + HHI_OFF);
  ushort*   hlo = (ushort*)(ws + HLO_OFF);
  unsigned* bar = (unsigned*)(ws + BAR_OFF) + bb * 16;

  // Fragment-linear W: whiF[((q*16 + kblk)*64 + lane)*8 + e] =
  //   W[q*16 + (lane&15)][kblk*32 + (lane>>4)*8 + e],  kblk = 0..15
  __shared__ ushort whiF[4 * 16 * 64 * 8];   // 64 KB
  __shared__ ushort wloF[4 * 16 * 64 * 8];   // 64 KB
  __shared__ float  gates2[2][4][MB][20];    // two-stage K-partials, pad 20
  __shared__ float  wih_s[NROW][3];
  __shared__ float  bsum[NROW];
  __shared__ float  xs[MB][3];
  __shared__ ushort hstg[MB][16];
  __shared__ ushort lstg[MB][16];

  if (tid < NROW) {
    int qq = tid >> 4, jj = tid & 15;
    int grow = qq * Hh + j0 + jj;
    wih_s[tid][0] = Wih[grow * 3 + 0];
    wih_s[tid][1] = Wih[grow * 3 + 1];
    wih_s[tid][2] = Wih[grow * 3 + 2];
    bsum[tid] = bih[grow] + bhh[grow];
  }

  for (int idx = tid; idx < NROW * 64; idx += NTHR) {
    int row = idx >> 6, seg = idx & 63;
    int qq = row >> 4, jj = row & 15;
    const float* src = Whh + (size_t)(qq * Hh + j0 + jj) * Hh + seg * 8;
    float4 w0 = *(const float4*)(src);
    float4 w1 = *(const float4*)(src + 4);
    float wv[8] = {w0.x, w0.y, w0.z, w0.w, w1.x, w1.y, w1.z, w1.w};
    unsigned uhi[4], ulo[4];
    #pragma unroll
    for (int p = 0; p < 4; ++p) {
      ushort h0 = f2bf(wv[2*p]),   h1 = f2bf(wv[2*p+1]);
      ushort l0 = f2bf(wv[2*p]   - bf2f(h0));
      ushort l1 = f2bf(wv[2*p+1] - bf2f(h1));
      uhi[p] = (unsigned)h0 | ((unsigned)h1 << 16);
      ulo[p] = (unsigned)l0 | ((unsigned)l1 << 16);
    }
    int kblk = seg >> 2, lkk = seg & 3;
    int dst = ((qq * 16 + kblk) * 64 + lkk * 16 + jj) * 8;
    *(uint4*)&whiF[dst] = make_uint4(uhi[0], uhi[1], uhi[2], uhi[3]);
    *(uint4*)&wloF[dst] = make_uint4(ulo[0], ulo[1], ulo[2], ulo[3]);
  }

  {
    int b = tid >> 4, jj = tid & 15;
    size_t o = (size_t)(b0 + b) * Hh + j0 + jj;
    __hip_atomic_store(&hhi[o], (ushort)0, __ATOMIC_RELAXED, __HIP_MEMORY_SCOPE_AGENT);
    __hip_atomic_store(&hlo[o], (ushort)0, __ATOMIC_RELAXED, __HIP_MEMORY_SCOPE_AGENT);
  }
  group_barrier(bar, tid, 32u);

  const int l   = tid & 63;
  const int wid = tid >> 6;
  const int m   = wid >> 2;            // batch half (0..1)
  const int ks  = wid & 3;             // K quarter (0..3)
  const int lm  = l & 15;
  const int lk  = l >> 4;              // 0..3

  const size_t aoff  = (size_t)(b0 + m * 16 + lm) * Hh + ks * 128 + lk * 8;
  const int    wq0   = ks * 2048 + l * 8;   // + q*8192 + u*512 (ushort idx)

  const int cb = tid >> 4;
  const int cj = tid & 15;
  float c_state = 0.0f;

  int cur = 0;
  for (int t = 0; t < Tt; ++t) {
    if (tid < MB * 3) {
      int b = tid / 3, ii = tid - b * 3;
      xs[b][ii] = x[(size_t)(b0 + b) * (Tt * 3) + t * 3 + ii];
    }

    // ---- 8 pipelined A loads (distinct K-quarter, hi+lo) ----
    const char* pH = (const char*)(hhi + (size_t)cur * Bsz * Hh + aoff);
    const char* pL = (const char*)(hlo + (size_t)cur * Bsz * Hh + aoff);
    f32x4 AH[4], AL[4];
    GLOAD(AH[0], pH, 0);  GLOAD(AH[1], pH, 64);  GLOAD(AH[2], pH, 128); GLOAD(AH[3], pH, 192);
    GLOAD(AL[0], pL, 0);  GLOAD(AL[1], pL, 64);  GLOAD(AL[2], pL, 128); GLOAD(AL[3], pL, 192);
    asm volatile("s_waitcnt vmcnt(0)" ::: "memory");
    __builtin_amdgcn_sched_barrier(0);

    // ---- 4 quadrants x 4 k-blocks x 3 split terms = 48 MFMAs ----
    f32x4 acc0 = {0.f,0.f,0.f,0.f}, acc1 = {0.f,0.f,0.f,0.f};
    f32x4 acc2 = {0.f,0.f,0.f,0.f}, acc3 = {0.f,0.f,0.f,0.f};
    #pragma unroll
    for (int u = 0; u < 4; ++u) {
      s16x8 ah = __builtin_bit_cast(s16x8, AH[u]);
      s16x8 al = __builtin_bit_cast(s16x8, AL[u]);
      const int fo = wq0 + u * 512;
      {
        s16x8 bh = *(const s16x8*)&whiF[0 * 8192 + fo];
        s16x8 bl = *(const s16x8*)&wloF[0 * 8192 + fo];
        acc0 = __builtin_amdgcn_mfma_f32_16x16x32_bf16(ah, bh, acc0, 0, 0, 0);
        acc0 = __builtin_amdgcn_mfma_f32_16x16x32_bf16(ah, bl, acc0, 0, 0, 0);
        acc0 = __builtin_amdgcn_mfma_f32_16x16x32_bf16(al, bh, acc0, 0, 0, 0);
      }
      {
        s16x8 bh = *(const s16x8*)&whiF[1 * 8192 + fo];
        s16x8 bl = *(const s16x8*)&wloF[1 * 8192 + fo];
        acc1 = __builtin_amdgcn_mfma_f32_16x16x32_bf16(ah, bh, acc1, 0, 0, 0);
        acc1 = __builtin_amdgcn_mfma_f32_16x16x32_bf16(ah, bl, acc1, 0, 0, 0);
        acc1 = __builtin_amdgcn_mfma_f32_16x16x32_bf16(al, bh, acc1, 0, 0, 0);
      }
      {
        s16x8 bh = *(const s16x8*)&whiF[2 * 8192 + fo];
        s16x8 bl = *(const s16x8*)&wloF[2 * 8192 + fo];
        acc2 = __builtin_amdgcn_mfma_f32_16x16x32_bf16(ah, bh, acc2, 0, 0, 0);
        acc2 = __builtin_amdgcn_mfma_f32_16x16x32_bf16(ah, bl, acc2, 0, 0, 0);
        acc2 = __builtin_amdgcn_mfma_f32_16x16x32_bf16(al, bh, acc2, 0, 0, 0);
      }
      {
        s16x8 bh = *(const s16x8*)&whiF[3 * 8192 + fo];
        s16x8 bl = *(const s16x8*)&wloF[3 * 8192 + fo];
        acc3 = __builtin_amdgcn_mfma_f32_16x16x32_bf16(ah, bh, acc3, 0, 0, 0);
        acc3 = __builtin_amdgcn_mfma_f32_16x16x32_bf16(ah, bl, acc3, 0, 0, 0);
        acc3 = __builtin_amdgcn_mfma_f32_16x16x32_bf16(al, bh, acc3, 0, 0, 0);
      }
    }

    // ---- two-stage K-partial reduction in LDS ----
    const int rrow = m * 16 + lk * 4;
    if (ks < 2) {
      #pragma unroll
      for (int r = 0; r < 4; ++r) {
        gates2[ks][0][rrow + r][lm] = acc0[r];
        gates2[ks][1][rrow + r][lm] = acc1[r];
        gates2[ks][2][rrow + r][lm] = acc2[r];
        gates2[ks][3][rrow + r][lm] = acc3[r];
      }
    }
    __syncthreads();
    if (ks >= 2) {
      #pragma unroll
      for (int r = 0; r < 4; ++r) {
        gates2[ks - 2][0][rrow + r][lm] += acc0[r];
        gates2[ks - 2][1][rrow + r][lm] += acc1[r];
        gates2[ks - 2][2][rrow + r][lm] += acc2[r];
        gates2[ks - 2][3][rrow + r][lm] += acc3[r];
      }
    }
    __syncthreads();

    // ---- gate combine ----
    {
      float xv0 = xs[cb][0], xv1 = xs[cb][1], xv2 = xs[cb][2];
      float pre[4];
      #pragma unroll
      for (int qq = 0; qq < 4; ++qq) {
        int r = qq * 16 + cj;
        pre[qq] = gates2[0][qq][cb][cj] + gates2[1][qq][cb][cj] + bsum[r]
                + xv0 * wih_s[r][0] + xv1 * wih_s[r][1] + xv2 * wih_s[r][2];
      }
      float ig = sigm(pre[0]), fg = sigm(pre[1]);
      float gg = tanhx(pre[2]), og = sigm(pre[3]);
      c_state = fg * c_state + ig * gg;
      float hv = og * tanhx(c_state);
      ushort uh = f2bf(hv);
      hstg[cb][cj] = uh;
      lstg[cb][cj] = f2bf(hv - bf2f(uh));
    }
    __syncthreads();

    if (tid < 256) {
      int b = tid >> 3, jp = tid & 7;
      unsigned wh = (unsigned)hstg[b][2 * jp] | ((unsigned)hstg[b][2 * jp + 1] << 16);
      unsigned wl = (unsigned)lstg[b][2 * jp] | ((unsigned)lstg[b][2 * jp + 1] << 16);
      size_t wordo = ((size_t)(cur ^ 1) * Bsz * Hh + (size_t)(b0 + b) * Hh + j0) / 2 + jp;
      __hip_atomic_store((unsigned*)hhi + wordo, wh, __ATOMIC_RELAXED, __HIP_MEMORY_SCOPE_AGENT);
      __hip_atomic_store((unsigned*)hlo + wordo, wl, __ATOMIC_RELAXED, __HIP_MEMORY_SCOPE_AGENT);
    }

    group_barrier(bar, tid, 32u * (t + 2));
    cur ^= 1;
  }

  if (hb == 0) {
    const u64* Hf = (const u64*)(hhi + (size_t)cur * Bsz * Hh);
    const u64* Lf = (const u64*)(hlo + (size_t)cur * Bsz * Hh);
    int b = tid >> 4, lj = tid & 15;
    float p = 0.0f;
    for (int jq = lj; jq < Hh / 4; jq += 16) {
      size_t o = (size_t)(b0 + b) * (Hh / 4) + jq;
      u64 uh = __hip_atomic_load(Hf + o, __ATOMIC_RELAXED, __HIP_MEMORY_SCOPE_AGENT);
      u64 ul = __hip_atomic_load(Lf + o, __ATOMIC_RELAXED, __HIP_MEMORY_SCOPE_AGENT);
      #pragma unroll
      for (int e = 0; e < 4; ++e) {
        float hv = bf2f((ushort)(uh >> (16 * e))) + bf2f((ushort)(ul >> (16 * e)));
        p += hv * fcw[4 * jq + e];
      }
    }
    __syncthreads();   // all waves done with gates2 before reuse
    ((float*)gates2)[tid] = p;
    __syncthreads();
    if (lj == 0) {
      float s = 0.0f;
      #pragma unroll
      for (int r = 0; r < 16; ++r) s += ((float*)gates2)[(b << 4) + r];
      out[b0 + b] = s + fcb[0];
    }
  }
}

extern "C" void kernel_launch(void* const* d_in, const int* in_sizes, int n_in,
                              void* d_out, int out_size, void* d_ws, size_t ws_size,
                              hipStream_t stream) {
  const float* x   = (const float*)d_in[0];
  const float* Wih = (const float*)d_in[1];
  const float* Whh = (const float*)d_in[2];
  const float* bih = (const float*)d_in[3];
  const float* bhh = (const float*)d_in[4];
  const float* fcw = (const float*)d_in[5];
  const float* fcb = (const float*)d_in[6];
  float* out = (float*)d_out;
  char*  ws  = (char*)d_ws;

  hipLaunchKernelGGL(init_ws, dim3(1), dim3(CTRL_UINTS), 0, stream,
                     (unsigned*)(ws + BAR_OFF));
  hipLaunchKernelGGL(lstm_kernel, dim3(NWG), dim3(NTHR), 0, stream,
                     x, Wih, Whh, bih, bhh, fcw, fcb, out, ws);
}